// Round 5
// baseline (281.532 us; speedup 1.0000x reference)
//
#include <hip/hip_runtime.h>
#include <stdint.h>

typedef __attribute__((ext_vector_type(8))) short short8;
typedef __attribute__((ext_vector_type(4))) short short4v;
typedef __attribute__((ext_vector_type(4))) float floatx4;

__device__ __forceinline__ unsigned short f2bf(float f) {
    unsigned int u = __float_as_uint(f);
    u += 0x7FFFu + ((u >> 16) & 1u);   // round-to-nearest-even
    return (unsigned short)(u >> 16);
}
__device__ __forceinline__ float bf2f(unsigned short s) {
    return __uint_as_float(((unsigned int)s) << 16);
}
__device__ __forceinline__ float sigmoidf(float x) {
    return 1.f / (1.f + __expf(-x));
}

// async 16B global -> LDS (DMA, no VGPR round-trip). LDS dest is
// wave-uniform base + lane*16 (pass the wave-uniform pointer).
__device__ __forceinline__ void async_load16(const short* g, short* l) {
    __builtin_amdgcn_global_load_lds(
        (const __attribute__((address_space(1))) unsigned int*)(uintptr_t)g,
        (__attribute__((address_space(3))) unsigned int*)(uintptr_t)l,
        16, 0, 0);
}

// Prologue: Wf|Wa fp32 [256,512] -> bf16, MFMA fragment order (usable as the
// A-operand: lane slot lk*16+l15 holds W[d=g*16+l15][k=ks*32+lk*8 .. +8]).
// short8 index = (g*16 + ks)*64 + lane.  g<16 -> Wf, g>=16 -> Wa.
__global__ __launch_bounds__(256)
void convert_w_kernel(const float* __restrict__ Wf,
                      const float* __restrict__ Wa,
                      short* __restrict__ wswz)
{
    int id = blockIdx.x * 256 + threadIdx.x;       // 32768 total
    int slot = id & 63;
    int ks   = (id >> 6) & 15;
    int g    = id >> 10;
    int l15  = slot & 15, lk = slot >> 4;
    const float* base = (g < 16) ? (Wf + (long)(g * 16 + l15) * 512)
                                 : (Wa + (long)((g - 16) * 16 + l15) * 512);
    const float* src = base + ks * 32 + lk * 8;
    floatx4 w0 = *(const floatx4*)src;
    floatx4 w1 = *(const floatx4*)(src + 4);
    short8 o;
    o[0] = (short)f2bf(w0[0]); o[1] = (short)f2bf(w0[1]);
    o[2] = (short)f2bf(w0[2]); o[3] = (short)f2bf(w0[3]);
    o[4] = (short)f2bf(w1[0]); o[5] = (short)f2bf(w1[1]);
    o[6] = (short)f2bf(w1[2]); o[7] = (short)f2bf(w1[3]);
    *(short8*)(wswz + (long)id * 8) = o;
}

// Mark updated rows.
__global__ __launch_bounds__(256)
void mark_kernel(const int* __restrict__ ei, const int* __restrict__ ti,
                 unsigned char* __restrict__ flags, int n)
{
    int i = blockIdx.x * 256 + threadIdx.x;
    if (i < n) flags[64 * ei[i] + ti[i]] = 1;
}

// Copy rows NOT updated (one wave per row; wave-uniform flag branch).
__global__ __launch_bounds__(256)
void copy_rest_kernel(const float* __restrict__ flat,
                      const unsigned char* __restrict__ flags,
                      float* __restrict__ out, int nrows)
{
    const int lane = threadIdx.x & 63;
    const int w0   = (blockIdx.x * 256 + threadIdx.x) >> 6;
    const int nw   = (gridDim.x * 256) >> 6;
    for (int row = w0; row < nrows; row += nw) {
        if (flags[row]) continue;
        const floatx4* s = (const floatx4*)(flat + (long)row * 256);
        floatx4*       o = (floatx4*)(out + (long)row * 256);
        o[lane] = s[lane];
    }
}

// Kernel 1 of split path: gather prev/upd, fp32->bf16, write dense A
// [n_occ, 512] bf16 with 16B chunks XOR-swizzled (chunk c of row occ lands
// at c ^ (occ&7)) so linear global_load_lds staging yields bank-conflict-free
// ds_read_b128 fragments downstream. Pure streaming: no LDS, no barriers.
__global__ __launch_bounds__(256)
void gather_convert_kernel(const float* __restrict__ flat,
                           const float* __restrict__ syms,
                           const int* __restrict__ ei,
                           const int* __restrict__ ti,
                           const int* __restrict__ si,
                           short* __restrict__ Adense, int n_occ)
{
    const int lane = threadIdx.x & 63;
    const int wid  = (blockIdx.x * 256 + threadIdx.x) >> 6;
    const int nw   = (gridDim.x * 256) >> 6;
    for (int occ = wid; occ < n_occ; occ += nw) {
        const int row = 64 * ei[occ] + ti[occ];       // wave-uniform
        const int sym = si[occ];
        // lanes 0-31: prev k = lane*8..+8 ; lanes 32-63: upd k' = (lane-32)*8..+8
        const float* src = (lane < 32)
            ? (flat + (long)row * 256 + lane * 8)
            : (syms + (long)sym * 256 + (lane - 32) * 8);
        floatx4 v0 = *(const floatx4*)src;
        floatx4 v1 = *(const floatx4*)(src + 4);
        short8 o;
        o[0] = (short)f2bf(v0[0]); o[1] = (short)f2bf(v0[1]);
        o[2] = (short)f2bf(v0[2]); o[3] = (short)f2bf(v0[3]);
        o[4] = (short)f2bf(v1[0]); o[5] = (short)f2bf(v1[1]);
        o[6] = (short)f2bf(v1[2]); o[7] = (short)f2bf(v1[3]);
        const int co = lane ^ (occ & 7);              // low-3-bit chunk xor
        *(short8*)(Adense + (long)occ * 512 + co * 8) = o;
    }
}

// Kernel 2 of split path: dense bf16 GEMM (Z^T: A=weights, B=concat rows) +
// sigmoid gates + gated combine + scatter.
// Block: 512 threads (8 waves), 64 rows, LDS exactly 64KB linear
// (chunk-swizzled content), staged via 8 async global_load_lds per thread.
// Wave wv owns d in [32wv, 32wv+32) for both gates (acc[4][4]).
__global__ __launch_bounds__(512, 4)
void gemm_gate_kernel(const short* __restrict__ Adense,  // [n_occ,512] swz
                      const float* __restrict__ bfb,
                      const float* __restrict__ bab,
                      const int* __restrict__ expr_idx,
                      const int* __restrict__ token_idx,
                      const short* __restrict__ wswz,
                      float* __restrict__ out)
{
    __shared__ __align__(16) short A_lds[64 * 512];   // 64KB exactly

    const int tid  = threadIdx.x;
    const int occ0 = blockIdx.x * 64;

    // ---- stage 64KB tile: 8 x 16B async DMA per thread, fully coalesced ----
    {
        const short* gbase = Adense + (long)occ0 * 512;
        const int wub = (tid & ~63) * 8;   // wave-uniform LDS short offset
        #pragma unroll
        for (int i = 0; i < 8; ++i)
            async_load16(gbase + i * 4096 + tid * 8, A_lds + i * 4096 + wub);
    }
    asm volatile("s_waitcnt vmcnt(0)" ::: "memory");
    __syncthreads();

    const int lane = tid & 63;
    const int wv   = tid >> 6;    // 0..7
    const int l15  = lane & 15;
    const int lk   = lane >> 4;   // 0..3

    floatx4 acc[4][4];            // [m-chunk][c: 0,1=forget, 2,3=add]
    #pragma unroll
    for (int mi = 0; mi < 4; ++mi)
        #pragma unroll
        for (int c = 0; c < 4; ++c)
            acc[mi][c] = (floatx4){0.f, 0.f, 0.f, 0.f};

    const short8* wsv = (const short8*)wswz;

    #pragma unroll
    for (int ks = 0; ks < 16; ++ks) {
        short8 cb[4];   // concat-row B-fragments (cols = m), swizzled read
        #pragma unroll
        for (int mi = 0; mi < 4; ++mi) {
            const int m = mi * 16 + l15;
            const int ch = ((ks << 2) | lk) ^ (m & 7);
            cb[mi] = *(const short8*)&A_lds[m * 512 + (ch << 3)];
        }
        #pragma unroll
        for (int c = 0; c < 4; ++c) {
            const int g = (c < 2) ? (wv * 2 + c) : (16 + wv * 2 + (c - 2));
            short8 wf = wsv[(g * 16 + ks) * 64 + lane];
            #pragma unroll
            for (int mi = 0; mi < 4; ++mi)
                acc[mi][c] = __builtin_amdgcn_mfma_f32_16x16x32_bf16(
                    wf, cb[mi], acc[mi][c], 0, 0, 0);
        }
    }

    // ---- epilogue: lane owns m = mi*16+l15, d = 32wv+16c+lk*4 .. +3 ----
    #pragma unroll
    for (int c = 0; c < 2; ++c) {
        const int d0 = wv * 32 + c * 16 + lk * 4;
        const floatx4 bfv = *(const floatx4*)(bfb + d0);
        const floatx4 bav = *(const floatx4*)(bab + d0);
        const int cp = d0 >> 3;          // prev chunk
        const int cu = 32 + (d0 >> 3);   // upd chunk
        const int sub = (lk & 1) * 4;    // short offset within chunk
        #pragma unroll
        for (int mi = 0; mi < 4; ++mi) {
            const int m = mi * 16 + l15;
            const int sw = m & 7;
            short4v pv = *(const short4v*)&A_lds[m * 512 + ((cp ^ sw) << 3) + sub];
            short4v uv = *(const short4v*)&A_lds[m * 512 + ((cu ^ sw) << 3) + sub];
            floatx4 res;
            #pragma unroll
            for (int j = 0; j < 4; ++j) {
                float fg = sigmoidf(acc[mi][c][j]     + bfv[j]);
                float ag = sigmoidf(acc[mi][c + 2][j] + bav[j]);
                res[j] = fg * bf2f((unsigned short)pv[j])
                       + ag * bf2f((unsigned short)uv[j]);
            }
            const int occ = occ0 + m;
            const long row = 64 * expr_idx[occ] + token_idx[occ];  // L1-hot
            *(floatx4*)(out + row * 256 + d0) = res;
        }
    }
}

// ---------- fallback (R4 fused path) if ws too small for dense A ----------
__global__ __launch_bounds__(512, 4)
void gate_gemm_fused_kernel(const float* __restrict__ flat,
                            const float* __restrict__ syms,
                            const float* __restrict__ bfb,
                            const float* __restrict__ bab,
                            const int* __restrict__ expr_idx,
                            const int* __restrict__ token_idx,
                            const int* __restrict__ sym_idx,
                            const short* __restrict__ wswz,
                            float* __restrict__ out)
{
    __shared__ __align__(16) short A_lds[64][520];
    __shared__ int rowbuf[64];
    __shared__ int symbuf[64];

    const int tid  = threadIdx.x;
    const int occ0 = blockIdx.x * 64;

    if (tid < 64) {
        int occ = occ0 + tid;
        rowbuf[tid] = 64 * expr_idx[occ] + token_idx[occ];
        symbuf[tid] = sym_idx[occ];
    }
    __syncthreads();
    {
        const int srow = tid >> 3;
        const int se   = tid & 7;
        const float* prow = flat + (long)rowbuf[srow] * 256;
        const float* urow = syms + (long)symbuf[srow] * 256;
        #pragma unroll
        for (int it = 0; it < 8; ++it) {
            const int k = (se + it * 8) * 4;
            floatx4 v = *(const floatx4*)(prow + k);
            short4v sv;
            sv[0] = (short)f2bf(v[0]); sv[1] = (short)f2bf(v[1]);
            sv[2] = (short)f2bf(v[2]); sv[3] = (short)f2bf(v[3]);
            *(short4v*)&A_lds[srow][k] = sv;
        }
        #pragma unroll
        for (int it = 0; it < 8; ++it) {
            const int k = (se + it * 8) * 4;
            floatx4 v = *(const floatx4*)(urow + k);
            short4v sv;
            sv[0] = (short)f2bf(v[0]); sv[1] = (short)f2bf(v[1]);
            sv[2] = (short)f2bf(v[2]); sv[3] = (short)f2bf(v[3]);
            *(short4v*)&A_lds[srow][256 + k] = sv;
        }
    }
    __syncthreads();

    const int lane = tid & 63;
    const int wv   = tid >> 6;
    const int l15  = lane & 15;
    const int lk   = lane >> 4;

    floatx4 acc[4][4];
    #pragma unroll
    for (int mi = 0; mi < 4; ++mi)
        #pragma unroll
        for (int c = 0; c < 4; ++c)
            acc[mi][c] = (floatx4){0.f, 0.f, 0.f, 0.f};

    const short8* wsv = (const short8*)wswz;

    #pragma unroll
    for (int ks = 0; ks < 16; ++ks) {
        short8 cb[4];
        #pragma unroll
        for (int mi = 0; mi < 4; ++mi)
            cb[mi] = *(const short8*)&A_lds[mi * 16 + l15][ks * 32 + lk * 8];
        #pragma unroll
        for (int c = 0; c < 4; ++c) {
            const int g = (c < 2) ? (wv * 2 + c) : (16 + wv * 2 + (c - 2));
            short8 wf = wsv[(g * 16 + ks) * 64 + lane];
            #pragma unroll
            for (int mi = 0; mi < 4; ++mi)
                acc[mi][c] = __builtin_amdgcn_mfma_f32_16x16x32_bf16(
                    wf, cb[mi], acc[mi][c], 0, 0, 0);
        }
    }
    #pragma unroll
    for (int c = 0; c < 2; ++c) {
        const int d0 = wv * 32 + c * 16 + lk * 4;
        const floatx4 bfv = *(const floatx4*)(bfb + d0);
        const floatx4 bav = *(const floatx4*)(bab + d0);
        #pragma unroll
        for (int mi = 0; mi < 4; ++mi) {
            const int m = mi * 16 + l15;
            short4v pv = *(const short4v*)&A_lds[m][d0];
            short4v uv = *(const short4v*)&A_lds[m][256 + d0];
            floatx4 res;
            #pragma unroll
            for (int j = 0; j < 4; ++j) {
                float fg = sigmoidf(acc[mi][c][j]     + bfv[j]);
                float ag = sigmoidf(acc[mi][c + 2][j] + bav[j]);
                res[j] = fg * bf2f((unsigned short)pv[j])
                       + ag * bf2f((unsigned short)uv[j]);
            }
            *(floatx4*)(out + (long)rowbuf[m] * 256 + d0) = res;
        }
    }
}

extern "C" void kernel_launch(void* const* d_in, const int* in_sizes, int n_in,
                              void* d_out, int out_size, void* d_ws, size_t ws_size,
                              hipStream_t stream) {
    const float* flat = (const float*)d_in[0];
    const float* syms = (const float*)d_in[1];
    const float* Wf   = (const float*)d_in[2];
    const float* bf   = (const float*)d_in[3];
    const float* Wa   = (const float*)d_in[4];
    const float* ba   = (const float*)d_in[5];
    const int* ei     = (const int*)d_in[6];
    const int* ti     = (const int*)d_in[7];
    const int* si     = (const int*)d_in[8];
    float* out        = (float*)d_out;

    short* wswz          = (short*)d_ws;                         // 512 KB
    unsigned char* flags = (unsigned char*)d_ws + 512 * 1024;    // 256 KB
    short* Adense        = (short*)((char*)d_ws + (1 << 20));    // 128 MB

    const int n_occ = in_sizes[6];        // 131072
    const int nrows = out_size / 256;     // 262144

    hipMemsetAsync(flags, 0, nrows, stream);
    mark_kernel<<<(n_occ + 255) / 256, 256, 0, stream>>>(ei, ti, flags, n_occ);
    convert_w_kernel<<<128, 256, 0, stream>>>(Wf, Wa, wswz);

    const size_t need = (size_t)(1 << 20) + (size_t)n_occ * 1024;
    if (ws_size >= need) {
        gather_convert_kernel<<<4096, 256, 0, stream>>>(flat, syms, ei, ti, si,
                                                        Adense, n_occ);
        gemm_gate_kernel<<<n_occ / 64, 512, 0, stream>>>(Adense, bf, ba,
                                                         ei, ti, wswz, out);
    } else {
        gate_gemm_fused_kernel<<<n_occ / 64, 512, 0, stream>>>(
            flat, syms, bf, ba, ei, ti, si, wswz, out);
    }

    copy_rest_kernel<<<2048, 256, 0, stream>>>(flat, flags, out, nrows);
}